// Round 10
// baseline (543.937 us; speedup 1.0000x reference)
//
#include <hip/hip_runtime.h>

#define NROWS 32768   // B*T
#define PD    512     // P_DIM
#define NCB   8       // NC
#define CSZ   256     // CS
#define TOTD  2048    // TOT
#define SIN   1792    // SELF_IN / SELF_OUT

typedef float floatx4  __attribute__((ext_vector_type(4)));
typedef float floatx16 __attribute__((ext_vector_type(16)));
typedef int   intx4    __attribute__((ext_vector_type(4)));
typedef int   intx8    __attribute__((ext_vector_type(8)));

__device__ __forceinline__ unsigned short f2bf(float f) {
    unsigned int u = __float_as_uint(f);
    u += 0x7FFFu + ((u >> 16) & 1u);
    return (unsigned short)(u >> 16);
}
// f32 -> fp8 e4m3 (single value, RNE, saturating)
__device__ __forceinline__ unsigned char f2fp8(float v) {
    int p = __builtin_amdgcn_cvt_pk_fp8_f32(v, v, 0, false);
    return (unsigned char)(p & 0xFF);
}

// async global->LDS, 16B per lane; LDS dest = wave-uniform base + lane*16
__device__ __forceinline__ void gload16(const unsigned char* g, unsigned char* l) {
    __builtin_amdgcn_global_load_lds(
        (const __attribute__((address_space(1))) void*)g,
        (__attribute__((address_space(3))) void*)l, 16, 0, 0);
}

// MFMA 32x32x64 f8f6f4 (cbsz=blgp=0 => e4m3 x e4m3), acc pinned to AGPRs so
// acc regs stay out of the arch-VGPR budget (round-2/3 spill lesson).
#define MFMA64(ACC, A, B)                                                     \
    asm volatile("v_mfma_f32_32x32x64_f8f6f4 %0, %1, %2, %0"                  \
                 : "+a"(ACC) : "v"(A), "v"(B))

#define SBAR() asm volatile("s_barrier" ::: "memory")

// ---------------- f32 -> fp8 conversion (8 elems/thread) ----------------
__global__ __launch_bounds__(256) void k_cvt8(const float* __restrict__ in,
                                              unsigned char* __restrict__ out,
                                              float scale, int n8) {
    int i = blockIdx.x * 256 + threadIdx.x;
    if (i >= n8) return;
    float4 a = ((const float4*)in)[2 * i];
    float4 b = ((const float4*)in)[2 * i + 1];
    int p0 = __builtin_amdgcn_cvt_pk_fp8_f32(a.x * scale, a.y * scale, 0, false);
    p0     = __builtin_amdgcn_cvt_pk_fp8_f32(a.z * scale, a.w * scale, p0, true);
    int p1 = __builtin_amdgcn_cvt_pk_fp8_f32(b.x * scale, b.y * scale, 0, false);
    p1     = __builtin_amdgcn_cvt_pk_fp8_f32(b.z * scale, b.w * scale, p1, true);
    int2 o; o.x = p0; o.y = p1;
    ((int2*)out)[i] = o;
}

// -------- transpose linear_self (1792x1792) f32 -> bf16 (PRE-SCALED x8) --------
// LSTb[in][out] = bf16(8 * linear_self[out][in]); the x8 keeps k_ln entirely
// in the 8x domain (Hraw8 already stores fp8(8*hidden)) -> no input rescale.
__global__ __launch_bounds__(256) void k_tb(const float* __restrict__ in,
                                            unsigned short* __restrict__ out) {
    __shared__ float t[32][33];
    int bx = blockIdx.x * 32, by = blockIdx.y * 32;
    int tx = threadIdx.x & 31, ty = threadIdx.x >> 5;
#pragma unroll
    for (int j = 0; j < 32; j += 8)
        t[ty + j][tx] = in[(size_t)(by + ty + j) * SIN + bx + tx];
    __syncthreads();
#pragma unroll
    for (int j = 0; j < 32; j += 8)
        out[(size_t)(bx + ty + j) * SIN + by + tx] = f2bf(8.f * t[tx][ty + j]);
}

// ROUND-4 SKELETON + XCD col-inner swizzle (measured best: 273.8us gemm2).
// 128x128 tile, 256 thr / 4 waves, wave tile 64x64 (2x2 MFMA, acc 64 AGPR
// pinned), TRIPLE buffer, ONE barrier + vmcnt(4) per K-iter, prefetch dist 2.
// r5-r8: thin waves (325), 8-wave 256^2 (356), fat 256x128 (395), operand
// assembly (372) ALL regress. Structure frozen.
//
// LDS layout per 8KB buffer (K=64 slab of 128 rows):
//   [tile T=row>>5 (4)][granule g (64)][32B]  byte = T*2048 + g*32
//   granule g holds row = T*32 + (sigma(g)&31), k bytes (g>>5)*32 .. +31,
//   sigma(g) = g ^ ((g&12)>>2)  (involution, mirrored write/read).
// Read: lane l loads intx8 at tilebase + ((l<<5) ^ ((l&12)<<3)) (two b128,
//   32B contiguous per lane -> feeds MFMA directly, no assembly movs).
//
// XCD-aware tile order (r9, -118MB FETCH): HW places bid on XCD bid%8;
// wg = (bid&7)*512 + (bid>>3), decoded COL-INNER (row0=wg>>4, col0=wg&15):
// each XCD runs one H row-panel's 16 col-blocks back-to-back (L2-resident).

// ---------------- GEMM1 (fp8): Hraw8 = fp8(8 * (pred @ W1^T + b1)) ----------------
__global__ __launch_bounds__(256)
void k_gemm1(const unsigned char* __restrict__ A,
             const unsigned char* __restrict__ Bw,
             const float* __restrict__ bias,
             unsigned char* __restrict__ Out) {
    const int K = PD;
    __shared__ __align__(16) unsigned char As[3 * 8192];
    __shared__ __align__(16) unsigned char Bs[3 * 8192];

    const int tid  = threadIdx.x;
    const int lane = tid & 63;
    const int wave = tid >> 6;
    const int wm = (wave >> 1) << 6;
    const int wn = (wave & 1) << 6;
    const int wg   = (blockIdx.x & 7) * 512 + (blockIdx.x >> 3);
    const int row0 = (wg >> 4) << 7;
    const int col0 = (wg & 15) << 7;

    floatx16 acc00 = 0.f, acc01 = 0.f, acc10 = 0.f, acc11 = 0.f;

    const int lh    = lane >> 1;
    const int srow  = ((wave >> 1) << 5) + (lh ^ ((lh & 12) >> 2));
    const int skoff = ((wave & 1) << 5) + ((lane & 1) << 4);
    const unsigned char* Ag  = A  + (size_t)(row0 + srow) * K + skoff;
    const unsigned char* Ag2 = Ag + (size_t)64 * K;
    const unsigned char* Bg  = Bw + (size_t)(col0 + srow) * K + skoff;
    const unsigned char* Bg2 = Bg + (size_t)64 * K;
    unsigned char* Al = As + wave * 1024;
    unsigned char* Bl = Bs + wave * 1024;

    gload16(Ag,        Al);
    gload16(Ag2,       Al + 4096);
    gload16(Bg,        Bl);
    gload16(Bg2,       Bl + 4096);
    gload16(Ag + 64,   Al + 8192);
    gload16(Ag2 + 64,  Al + 8192 + 4096);
    gload16(Bg + 64,   Bl + 8192);
    gload16(Bg2 + 64,  Bl + 8192 + 4096);

    const int ro = (lane << 5) ^ ((lane & 12) << 3);

    auto compute = [&](int cbuf) {
        const unsigned char* Ab = As + cbuf * 8192 + ((wm >> 5) << 11) + ro;
        const unsigned char* Bb = Bs + cbuf * 8192 + ((wn >> 5) << 11) + ro;
        intx8 a0 = *(const intx8*)Ab;
        intx8 b0 = *(const intx8*)Bb;
        intx8 a1 = *(const intx8*)(Ab + 2048);
        intx8 b1 = *(const intx8*)(Bb + 2048);
        MFMA64(acc00, a0, b0);
        MFMA64(acc10, a1, b0);
        MFMA64(acc01, a0, b1);
        MFMA64(acc11, a1, b1);
    };

    const int NI = K / 64;   // 8
    int cb = 0, nb = 2;
    for (int i = 0; i < NI - 1; ++i) {
        asm volatile("s_waitcnt vmcnt(4)" ::: "memory");
        SBAR();
        if (i + 2 < NI) {
            const int k0 = (i + 2) * 64;
            gload16(Ag + k0,  Al + nb * 8192);
            gload16(Ag2 + k0, Al + nb * 8192 + 4096);
            gload16(Bg + k0,  Bl + nb * 8192);
            gload16(Bg2 + k0, Bl + nb * 8192 + 4096);
        }
        compute(cb);
        cb = (cb + 1 == 3) ? 0 : cb + 1;
        nb = (nb + 1 == 3) ? 0 : nb + 1;
    }
    asm volatile("s_waitcnt vmcnt(0)" ::: "memory");
    SBAR();
    compute(cb);
    asm volatile("s_nop 7\n\ts_nop 7\n\ts_nop 7" ::: "memory");  // MFMA->VALU read spacing

    // epilogue: hidden = acc/16 + b1; store fp8(8*hidden)
    const int l31  = lane & 31;
    const int half = lane >> 5;
    auto epi = [&](const floatx16& A0, const floatx16& A1, int mtoff) {
        const int col = col0 + wn + l31;
        const float bc0 = bias[col];
        const float bc1 = bias[col + 32];
#pragma unroll
        for (int r = 0; r < 16; ++r) {
            const int row = row0 + wm + mtoff + (r & 3) + ((r >> 2) << 3) + (half << 2);
            Out[(size_t)row * TOTD + col]      = f2fp8((A0[r] * 0.0625f + bc0) * 8.f);
            Out[(size_t)row * TOTD + col + 32] = f2fp8((A1[r] * 0.0625f + bc1) * 8.f);
        }
    };
    epi(acc00, acc01, 0);
    epi(acc10, acc11, 32);
}

// -------- fused: self-gather + relu + LayerNorm; fp8 in (x8) -> fp8 out (x8) --------
// All math in the 8x domain (x8 = 8*hidden): no input rescale; LSTb holds
// 8*W_self; LN absorbs the scale exactly via rstd' = rsqrt(var8 + 64*eps).
// bf16 unpack is 2 ops/elem (shl / and-mask). Channel loop bound is
// wave-uniform cmax = 2*wave+1 (max gt in wave) -> 16 executed wave-iters.
__global__ __launch_bounds__(256) void k_ln(const unsigned char* __restrict__ Hraw8,
                                            unsigned char* __restrict__ H8,
                                            const unsigned short* __restrict__ LSTb,
                                            const int* __restrict__ idx,
                                            const float* __restrict__ gamma,
                                            const float* __restrict__ beta) {
    const int row = blockIdx.x;
    const int tid = threadIdx.x;
    __shared__ int sidx[8];
    __shared__ float ws4[4], wss4[4];
    if (tid < 8) sidx[tid] = idx[(size_t)row * NCB + tid];

    uint2 w = ((const uint2*)(Hraw8 + (size_t)row * TOTD))[tid];
    float x[8];
    x[0] = __builtin_amdgcn_cvt_f32_fp8(w.x, 0);
    x[1] = __builtin_amdgcn_cvt_f32_fp8(w.x, 1);
    x[2] = __builtin_amdgcn_cvt_f32_fp8(w.x, 2);
    x[3] = __builtin_amdgcn_cvt_f32_fp8(w.x, 3);
    x[4] = __builtin_amdgcn_cvt_f32_fp8(w.y, 0);
    x[5] = __builtin_amdgcn_cvt_f32_fp8(w.y, 1);
    x[6] = __builtin_amdgcn_cvt_f32_fp8(w.y, 2);
    x[7] = __builtin_amdgcn_cvt_f32_fp8(w.y, 3);
    __syncthreads();

    const int gt   = tid >> 5;
    const int cmax = ((tid >> 6) << 1) + 1;   // wave-uniform
    for (int c = 0; c < cmax; ++c) {
        if (c < gt) {
            int ic = sidx[c];
            if (ic >= 0) {
                uint4 v = *(const uint4*)(LSTb + (size_t)(c * CSZ + ic) * SIN + (tid * 8 - CSZ));
                x[0] += __uint_as_float(v.x << 16);
                x[1] += __uint_as_float(v.x & 0xFFFF0000u);
                x[2] += __uint_as_float(v.y << 16);
                x[3] += __uint_as_float(v.y & 0xFFFF0000u);
                x[4] += __uint_as_float(v.z << 16);
                x[5] += __uint_as_float(v.z & 0xFFFF0000u);
                x[6] += __uint_as_float(v.w << 16);
                x[7] += __uint_as_float(v.w & 0xFFFF0000u);
            }
        }
    }
#pragma unroll
    for (int e = 0; e < 8; ++e) x[e] = fmaxf(x[e], 0.f);

    float s = 0.f, ss = 0.f;
#pragma unroll
    for (int e = 0; e < 8; ++e) { s += x[e]; ss += x[e] * x[e]; }
#pragma unroll
    for (int o = 32; o; o >>= 1) { s += __shfl_xor(s, o); ss += __shfl_xor(ss, o); }
    if ((tid & 63) == 0) { ws4[tid >> 6] = s; wss4[tid >> 6] = ss; }
    __syncthreads();
    s  = ws4[0] + ws4[1] + ws4[2] + ws4[3];
    ss = wss4[0] + wss4[1] + wss4[2] + wss4[3];
    const float mu8  = s * (1.f / TOTD);
    const float var8 = ss * (1.f / TOTD) - mu8 * mu8;
    const float rstd = rsqrtf(var8 + 64.f * 1e-5f);   // = 1/(8*sqrt(var+eps))... exact x8 absorb
    float y[8];
#pragma unroll
    for (int e = 0; e < 8; ++e) {
        int col = tid * 8 + e;
        float t = (x[e] - mu8) * rstd;                 // normalized value
        y[e] = (t * gamma[col] + beta[col]) * 8.f;     // H scale 8
    }
    int p0 = __builtin_amdgcn_cvt_pk_fp8_f32(y[0], y[1], 0, false);
    p0     = __builtin_amdgcn_cvt_pk_fp8_f32(y[2], y[3], p0, true);
    int p1 = __builtin_amdgcn_cvt_pk_fp8_f32(y[4], y[5], 0, false);
    p1     = __builtin_amdgcn_cvt_pk_fp8_f32(y[6], y[7], p1, true);
    int2 o; o.x = p0; o.y = p1;
    ((int2*)(H8 + (size_t)row * TOTD))[tid] = o;
}

// ------- GEMM2 (fp8): 128x128 tile, r4 pipeline + partial-softmax epilogue -------
__global__ __launch_bounds__(256)
void k_gemm2(const unsigned char* __restrict__ H,
             const unsigned char* __restrict__ W2,
             const float* __restrict__ b2,
             const int* __restrict__ idx,
             float* __restrict__ pm_,
             float* __restrict__ ps_,
             float* __restrict__ pt_) {
    const int K = TOTD;
    __shared__ __align__(16) unsigned char As[3 * 8192];
    __shared__ __align__(16) unsigned char Bs[3 * 8192];
    __shared__ int tidx[128];

    const int tid  = threadIdx.x;
    const int lane = tid & 63;
    const int wave = tid >> 6;
    const int wm = (wave >> 1) << 6;
    const int wn = (wave & 1) << 6;
    const int wg   = (blockIdx.x & 7) * 512 + (blockIdx.x >> 3);
    const int row0 = (wg >> 4) << 7;
    const int col0 = (wg & 15) << 7;
    const int g    = col0 >> 8;

    floatx16 acc00 = 0.f, acc01 = 0.f, acc10 = 0.f, acc11 = 0.f;

    const int lh    = lane >> 1;
    const int srow  = ((wave >> 1) << 5) + (lh ^ ((lh & 12) >> 2));
    const int skoff = ((wave & 1) << 5) + ((lane & 1) << 4);
    const unsigned char* Ag  = H  + (size_t)(row0 + srow) * K + skoff;
    const unsigned char* Ag2 = Ag + (size_t)64 * K;
    const unsigned char* Bg  = W2 + (size_t)(col0 + srow) * K + skoff;
    const unsigned char* Bg2 = Bg + (size_t)64 * K;
    unsigned char* Al = As + wave * 1024;
    unsigned char* Bl = Bs + wave * 1024;

    if (tid < 128) tidx[tid] = idx[(size_t)(row0 + tid) * NCB + g];

    gload16(Ag,        Al);
    gload16(Ag2,       Al + 4096);
    gload16(Bg,        Bl);
    gload16(Bg2,       Bl + 4096);
    gload16(Ag + 64,   Al + 8192);
    gload16(Ag2 + 64,  Al + 8192 + 4096);
    gload16(Bg + 64,   Bl + 8192);
    gload16(Bg2 + 64,  Bl + 8192 + 4096);

    const int ro = (lane << 5) ^ ((lane & 12) << 3);

    auto compute = [&](int cbuf) {
        const unsigned char* Ab = As + cbuf * 8192 + ((wm >> 5) << 11) + ro;
        const unsigned char* Bb = Bs + cbuf * 8192 + ((wn >> 5) << 11) + ro;
        intx8 a0 = *(const intx8*)Ab;
        intx8 b0 = *(const intx8*)Bb;
        intx8 a1 = *(const intx8*)(Ab + 2048);
        intx8 b1 = *(const intx8*)(Bb + 2048);
        MFMA64(acc00, a0, b0);
        MFMA64(acc10, a1, b0);
        MFMA64(acc01, a0, b1);
        MFMA64(acc11, a1, b1);
    };

    const int NI = K / 64;   // 32
    int cb = 0, nb = 2;
    for (int i = 0; i < NI - 1; ++i) {
        asm volatile("s_waitcnt vmcnt(4)" ::: "memory");
        SBAR();
        if (i + 2 < NI) {
            const int k0 = (i + 2) * 64;
            gload16(Ag + k0,  Al + nb * 8192);
            gload16(Ag2 + k0, Al + nb * 8192 + 4096);
            gload16(Bg + k0,  Bl + nb * 8192);
            gload16(Bg2 + k0, Bl + nb * 8192 + 4096);
        }
        compute(cb);
        cb = (cb + 1 == 3) ? 0 : cb + 1;
        nb = (nb + 1 == 3) ? 0 : nb + 1;
    }
    asm volatile("s_waitcnt vmcnt(0)" ::: "memory");
    SBAR();
    compute(cb);
    asm volatile("s_nop 7\n\ts_nop 7\n\ts_nop 7" ::: "memory");  // MFMA->VALU read spacing

    // ---- epilogue: per-row partials over this wave's 64-col window ----
    const int l31  = lane & 31;
    const int half = lane >> 5;
    const int slot = (col0 + wn) >> 6;   // 0..31
    const int coff = (col0 & 255) + wn;
    const float bc0 = b2[col0 + wn + l31];
    const float bc1 = b2[col0 + wn + 32 + l31];

    auto epi = [&](const floatx16& A0, const floatx16& A1, int mtoff) {
#pragma unroll
        for (int r = 0; r < 16; ++r) {
            const int lrow = wm + mtoff + (r & 3) + ((r >> 2) << 3) + (half << 2);
            const int ic   = tidx[lrow];
            const int tloc = ic - coff;
            float v0 = A0[r] * 0.0078125f + bc0;
            float v1 = A1[r] * 0.0078125f + bc1;
            float mm = fmaxf(v0, v1), tv = 0.f;
            if (ic >= 0) {
                if (l31 == tloc)      tv += v0;
                if (l31 + 32 == tloc) tv += v1;
            }
#pragma unroll
            for (int o = 1; o < 32; o <<= 1) mm = fmaxf(mm, __shfl_xor(mm, o));
            float sv = __expf(v0 - mm) + __expf(v1 - mm);
#pragma unroll
            for (int o = 1; o < 32; o <<= 1) { sv += __shfl_xor(sv, o); tv += __shfl_xor(tv, o); }
            if (l31 == 0) {
                const int row = row0 + lrow;
                pm_[(size_t)slot * NROWS + row] = mm;
                ps_[(size_t)slot * NROWS + row] = sv;
                pt_[(size_t)slot * NROWS + row] = tv;
            }
        }
    };
    epi(acc00, acc01, 0);
    epi(acc10, acc11, 32);
}

// ------- combine: merge 4 slots per (row, group), accumulate logprob + count -------
__global__ __launch_bounds__(256) void k_comb(const float* __restrict__ pm_,
                                              const float* __restrict__ ps_,
                                              const float* __restrict__ pt_,
                                              const int* __restrict__ idx,
                                              float* __restrict__ out) {
    const int i   = blockIdx.x * 256 + threadIdx.x;
    const int row = i & (NROWS - 1);
    const int g   = i >> 15;
    const int ic  = idx[(size_t)row * NCB + g];
    float lp = 0.f, cnt = 0.f;
    if (ic >= 0) {
        const size_t b = (size_t)(g * 4) * NROWS + row;
        float m0 = pm_[b], m1 = pm_[b + NROWS], m2 = pm_[b + 2 * NROWS], m3 = pm_[b + 3 * NROWS];
        float mm = fmaxf(fmaxf(m0, m1), fmaxf(m2, m3));
        float Z = ps_[b] * __expf(m0 - mm) + ps_[b + NROWS] * __expf(m1 - mm)
                + ps_[b + 2 * NROWS] * __expf(m2 - mm) + ps_[b + 3 * NROWS] * __expf(m3 - mm);
        float t = pt_[b] + pt_[b + NROWS] + pt_[b + 2 * NROWS] + pt_[b + 3 * NROWS];
        lp = t - (mm + __logf(Z));
        cnt = 1.f;
    }
#pragma unroll
    for (int o = 1; o < 64; o <<= 1) { lp += __shfl_xor(lp, o); cnt += __shfl_xor(cnt, o); }
    __shared__ float wred[8];
    const int lane = threadIdx.x & 63, wave = threadIdx.x >> 6;
    if (lane == 0) { wred[wave] = lp; wred[4 + wave] = cnt; }
    __syncthreads();
    if (threadIdx.x == 0) {
        atomicAdd(&out[0], wred[0] + wred[1] + wred[2] + wred[3]);
        atomicAdd(&out[1], wred[4] + wred[5] + wred[6] + wred[7]);
    }
}

extern "C" void kernel_launch(void* const* d_in, const int* in_sizes, int n_in,
                              void* d_out, int out_size, void* d_ws, size_t ws_size,
                              hipStream_t stream) {
    const float* predictor = (const float*)d_in[0];
    const int*   cbidx     = (const int*)d_in[1];
    const float* W1        = (const float*)d_in[2];
    const float* b1        = (const float*)d_in[3];
    const float* LS        = (const float*)d_in[4];
    const float* gamma     = (const float*)d_in[5];
    const float* beta      = (const float*)d_in[6];
    const float* W2        = (const float*)d_in[7];
    const float* b2        = (const float*)d_in[8];
    float* out = (float*)d_out;

    char* ws = (char*)d_ws;
    size_t off = 0;
    auto alloc = [&](size_t bytes) {
        char* p = ws + off;
        off += (bytes + 255) & ~(size_t)255;
        return p;
    };
    unsigned char* Hraw8 = (unsigned char*)alloc((size_t)NROWS * TOTD);   // dead after k_ln -> pm/ps/pt alias
    unsigned char* R2    = (unsigned char*)alloc((size_t)NROWS * TOTD);   // pred8+W1_8, then H8
    unsigned char* W2_8  = (unsigned char*)alloc((size_t)TOTD * TOTD);
    unsigned short* LSTb = (unsigned short*)alloc((size_t)SIN * SIN * 2);

    unsigned char* pred8 = R2;
    unsigned char* W1_8  = R2 + (size_t)NROWS * PD;
    unsigned char* H8    = R2;
    float* pm_ = (float*)Hraw8;
    float* ps_ = pm_ + (size_t)32 * NROWS;
    float* pt_ = ps_ + (size_t)32 * NROWS;

    hipMemsetAsync(d_out, 0, 2 * sizeof(float), stream);

    k_cvt8<<<NROWS * PD / 8 / 256, 256, 0, stream>>>(predictor, pred8, 1.f, NROWS * PD / 8);
    k_cvt8<<<TOTD * PD / 8 / 256, 256, 0, stream>>>(W1, W1_8, 16.f, TOTD * PD / 8);
    k_cvt8<<<TOTD * TOTD / 8 / 256, 256, 0, stream>>>(W2, W2_8, 16.f, TOTD * TOTD / 8);
    k_tb<<<dim3(SIN / 32, SIN / 32), 256, 0, stream>>>(LS, LSTb);

    k_gemm1<<<16 * 256, 256, 0, stream>>>(pred8, W1_8, b1, Hraw8);
    k_ln<<<NROWS, 256, 0, stream>>>(Hraw8, H8, LSTb, cbidx, gamma, beta);
    k_gemm2<<<16 * 256, 256, 0, stream>>>(H8, W2_8, b2, cbidx, pm_, ps_, pt_);
    k_comb<<<NROWS * NCB / 256, 256, 0, stream>>>(pm_, ps_, pt_, cbidx, out);
}

// Round 11
// 542.366 us; speedup vs baseline: 1.0029x; 1.0029x over previous
//
#include <hip/hip_runtime.h>

#define NROWS 32768   // B*T
#define PD    512     // P_DIM
#define NCB   8       // NC
#define CSZ   256     // CS
#define TOTD  2048    // TOT
#define SIN   1792    // SELF_IN / SELF_OUT

#define NPRED (NROWS * PD / 8)     // 2097152
#define NW1C  (TOTD * PD / 8)      // 131072
#define NW2C  (TOTD * TOTD / 8)    // 524288

typedef float floatx4  __attribute__((ext_vector_type(4)));
typedef float floatx16 __attribute__((ext_vector_type(16)));
typedef int   intx4    __attribute__((ext_vector_type(4)));
typedef int   intx8    __attribute__((ext_vector_type(8)));

__device__ __forceinline__ unsigned short f2bf(float f) {
    unsigned int u = __float_as_uint(f);
    u += 0x7FFFu + ((u >> 16) & 1u);
    return (unsigned short)(u >> 16);
}

// async global->LDS, 16B per lane; LDS dest = wave-uniform base + lane*16
__device__ __forceinline__ void gload16(const unsigned char* g, unsigned char* l) {
    __builtin_amdgcn_global_load_lds(
        (const __attribute__((address_space(1))) void*)g,
        (__attribute__((address_space(3))) void*)l, 16, 0, 0);
}

// MFMA 32x32x64 f8f6f4 (cbsz=blgp=0 => e4m3 x e4m3), acc pinned to AGPRs so
// acc regs stay out of the arch-VGPR budget (round-2/3 spill lesson).
#define MFMA64(ACC, A, B)                                                     \
    asm volatile("v_mfma_f32_32x32x64_f8f6f4 %0, %1, %2, %0"                  \
                 : "+a"(ACC) : "v"(A), "v"(B))

#define SBAR() asm volatile("s_barrier" ::: "memory")

// ------- merged f32 -> fp8 conversion for pred / W1 / W2 (8 elems/thread) -------
__global__ __launch_bounds__(256) void k_cvtall(const float* __restrict__ pred,
                                                const float* __restrict__ W1,
                                                const float* __restrict__ W2,
                                                unsigned char* __restrict__ pred8,
                                                unsigned char* __restrict__ W18,
                                                unsigned char* __restrict__ W28) {
    int i = blockIdx.x * 256 + threadIdx.x;
    const float* in; unsigned char* out; float scale; int j;
    if (i < NPRED)              { in = pred; out = pred8; scale = 1.f;  j = i; }
    else if (i < NPRED + NW1C)  { in = W1;   out = W18;   scale = 16.f; j = i - NPRED; }
    else                        { in = W2;   out = W28;   scale = 16.f; j = i - NPRED - NW1C; }
    float4 a = ((const float4*)in)[2 * j];
    float4 b = ((const float4*)in)[2 * j + 1];
    int p0 = __builtin_amdgcn_cvt_pk_fp8_f32(a.x * scale, a.y * scale, 0, false);
    p0     = __builtin_amdgcn_cvt_pk_fp8_f32(a.z * scale, a.w * scale, p0, true);
    int p1 = __builtin_amdgcn_cvt_pk_fp8_f32(b.x * scale, b.y * scale, 0, false);
    p1     = __builtin_amdgcn_cvt_pk_fp8_f32(b.z * scale, b.w * scale, p1, true);
    int2 o; o.x = p0; o.y = p1;
    ((int2*)out)[j] = o;
}

// -------- transpose linear_self (1792x1792) f32 -> bf16 (PRE-SCALED x8) --------
// LSTb[in][out] = bf16(8 * linear_self[out][in]); keeps k_ln in the 8x domain.
__global__ __launch_bounds__(256) void k_tb(const float* __restrict__ in,
                                            unsigned short* __restrict__ out) {
    __shared__ float t[32][33];
    int bx = blockIdx.x * 32, by = blockIdx.y * 32;
    int tx = threadIdx.x & 31, ty = threadIdx.x >> 5;
#pragma unroll
    for (int j = 0; j < 32; j += 8)
        t[ty + j][tx] = in[(size_t)(by + ty + j) * SIN + bx + tx];
    __syncthreads();
#pragma unroll
    for (int j = 0; j < 32; j += 8)
        out[(size_t)(bx + ty + j) * SIN + by + tx] = f2bf(8.f * t[tx][ty + j]);
}

// ROUND-4 SKELETON + XCD col-inner swizzle (measured best: 273.8us gemm2).
// 128x128 tile, 256 thr / 4 waves, wave tile 64x64 (2x2 MFMA, acc 64 AGPR
// pinned), TRIPLE buffer, ONE barrier + vmcnt(4) per K-iter, prefetch dist 2.
// r5-r8: thin waves (325), 8-wave 256^2 (356), fat 256x128 (395), operand
// assembly (372) ALL regress. GEMM loop structure frozen.
//
// LDS layout per 8KB buffer (K=64 slab of 128 rows):
//   [tile T=row>>5 (4)][granule g (64)][32B]  byte = T*2048 + g*32
//   granule g holds row = T*32 + (sigma(g)&31), k bytes (g>>5)*32 .. +31,
//   sigma(g) = g ^ ((g&12)>>2)  (involution, mirrored write/read).
// Read: lane l loads intx8 at tilebase + ((l<<5) ^ ((l&12)<<3)) (two b128,
//   32B contiguous per lane -> feeds MFMA directly, no assembly movs).
//
// XCD-aware tile order (r9, -118MB FETCH): HW places bid on XCD bid%8;
// wg = (bid&7)*512 + (bid>>3), decoded COL-INNER (row0=wg>>4, col0=wg&15).
//
// Hraw QUAD layout (r11): byte(row,col) lives at dword [(row>>2)*TOTD + col],
// byte lane row&3. gemm1 epilogue packs each 4-row column quad into one dword
// (2x cvt_pk_fp8) -> 16 coalesced dword stores/thread instead of 64 byte
// stores + 64 cvt. k_ln reads quads back 32B-contiguous per thread.

// ---------------- GEMM1 (fp8): HrawQ = quad-packed fp8(8 * (pred @ W1^T + b1)) ----------------
__global__ __launch_bounds__(256)
void k_gemm1(const unsigned char* __restrict__ A,
             const unsigned char* __restrict__ Bw,
             const float* __restrict__ bias,
             unsigned char* __restrict__ OutQ) {
    const int K = PD;
    __shared__ __align__(16) unsigned char As[3 * 8192];
    __shared__ __align__(16) unsigned char Bs[3 * 8192];

    const int tid  = threadIdx.x;
    const int lane = tid & 63;
    const int wave = tid >> 6;
    const int wm = (wave >> 1) << 6;
    const int wn = (wave & 1) << 6;
    const int wg   = (blockIdx.x & 7) * 512 + (blockIdx.x >> 3);
    const int row0 = (wg >> 4) << 7;
    const int col0 = (wg & 15) << 7;

    floatx16 acc00 = 0.f, acc01 = 0.f, acc10 = 0.f, acc11 = 0.f;

    const int lh    = lane >> 1;
    const int srow  = ((wave >> 1) << 5) + (lh ^ ((lh & 12) >> 2));
    const int skoff = ((wave & 1) << 5) + ((lane & 1) << 4);
    const unsigned char* Ag  = A  + (size_t)(row0 + srow) * K + skoff;
    const unsigned char* Ag2 = Ag + (size_t)64 * K;
    const unsigned char* Bg  = Bw + (size_t)(col0 + srow) * K + skoff;
    const unsigned char* Bg2 = Bg + (size_t)64 * K;
    unsigned char* Al = As + wave * 1024;
    unsigned char* Bl = Bs + wave * 1024;

    gload16(Ag,        Al);
    gload16(Ag2,       Al + 4096);
    gload16(Bg,        Bl);
    gload16(Bg2,       Bl + 4096);
    gload16(Ag + 64,   Al + 8192);
    gload16(Ag2 + 64,  Al + 8192 + 4096);
    gload16(Bg + 64,   Bl + 8192);
    gload16(Bg2 + 64,  Bl + 8192 + 4096);

    const int ro = (lane << 5) ^ ((lane & 12) << 3);

    auto compute = [&](int cbuf) {
        const unsigned char* Ab = As + cbuf * 8192 + ((wm >> 5) << 11) + ro;
        const unsigned char* Bb = Bs + cbuf * 8192 + ((wn >> 5) << 11) + ro;
        intx8 a0 = *(const intx8*)Ab;
        intx8 b0 = *(const intx8*)Bb;
        intx8 a1 = *(const intx8*)(Ab + 2048);
        intx8 b1 = *(const intx8*)(Bb + 2048);
        MFMA64(acc00, a0, b0);
        MFMA64(acc10, a1, b0);
        MFMA64(acc01, a0, b1);
        MFMA64(acc11, a1, b1);
    };

    const int NI = K / 64;   // 8
    int cb = 0, nb = 2;
    for (int i = 0; i < NI - 1; ++i) {
        asm volatile("s_waitcnt vmcnt(4)" ::: "memory");
        SBAR();
        if (i + 2 < NI) {
            const int k0 = (i + 2) * 64;
            gload16(Ag + k0,  Al + nb * 8192);
            gload16(Ag2 + k0, Al + nb * 8192 + 4096);
            gload16(Bg + k0,  Bl + nb * 8192);
            gload16(Bg2 + k0, Bl + nb * 8192 + 4096);
        }
        compute(cb);
        cb = (cb + 1 == 3) ? 0 : cb + 1;
        nb = (nb + 1 == 3) ? 0 : nb + 1;
    }
    asm volatile("s_waitcnt vmcnt(0)" ::: "memory");
    SBAR();
    compute(cb);
    asm volatile("s_nop 7\n\ts_nop 7\n\ts_nop 7" ::: "memory");  // MFMA->VALU read spacing

    // epilogue: store quad-packed fp8(8*hidden) = fp8(acc*0.5 + 8*b1)
    const int l31  = lane & 31;
    const int half = lane >> 5;
    unsigned int* Oq = (unsigned int*)OutQ;
    auto epi = [&](const floatx16& A0, const floatx16& A1, int mtoff) {
        const int col = col0 + wn + l31;
        const float bc0 = bias[col] * 8.f;
        const float bc1 = bias[col + 32] * 8.f;
        const int qbase = ((row0 + wm + mtoff) >> 2) + half;   // + 2q below
#pragma unroll
        for (int q = 0; q < 4; ++q) {
            int p0 = __builtin_amdgcn_cvt_pk_fp8_f32(A0[4 * q + 0] * 0.5f + bc0,
                                                     A0[4 * q + 1] * 0.5f + bc0, 0, false);
            p0     = __builtin_amdgcn_cvt_pk_fp8_f32(A0[4 * q + 2] * 0.5f + bc0,
                                                     A0[4 * q + 3] * 0.5f + bc0, p0, true);
            int p1 = __builtin_amdgcn_cvt_pk_fp8_f32(A1[4 * q + 0] * 0.5f + bc1,
                                                     A1[4 * q + 1] * 0.5f + bc1, 0, false);
            p1     = __builtin_amdgcn_cvt_pk_fp8_f32(A1[4 * q + 2] * 0.5f + bc1,
                                                     A1[4 * q + 3] * 0.5f + bc1, p1, true);
            Oq[(size_t)(qbase + 2 * q) * TOTD + col]      = p0;
            Oq[(size_t)(qbase + 2 * q) * TOTD + col + 32] = p1;
        }
    };
    epi(acc00, acc01, 0);
    epi(acc10, acc11, 32);
}

// -------- fused: self-gather + relu + LayerNorm; quad fp8 in -> row-major fp8 out --------
// 4 rows (one quad-row) per block; thread tid owns cols 8tid..8tid+7 of all 4
// rows (32B contiguous quad read). Math in the 8x domain (r10): LSTb holds
// 8*W_self; rstd' = rsqrt(var8 + 64*eps) absorbs the scale exactly.
__global__ __launch_bounds__(256) void k_ln(const unsigned char* __restrict__ HrawQ,
                                            unsigned char* __restrict__ H8,
                                            const unsigned short* __restrict__ LSTb,
                                            const int* __restrict__ idx,
                                            const float* __restrict__ gamma,
                                            const float* __restrict__ beta) {
    const int qrow = blockIdx.x;          // rows 4*qrow .. 4*qrow+3
    const int tid  = threadIdx.x;
    __shared__ int sidx[4][8];
    __shared__ float wsum[4][4], wsq[4][4];   // [wave][row]
    if (tid < 32)
        sidx[tid >> 3][tid & 7] = idx[(size_t)(4 * qrow + (tid >> 3)) * NCB + (tid & 7)];

    const uint4* Qp = (const uint4*)(HrawQ + (size_t)qrow * TOTD * 4) + 2 * tid;
    uint4 qa = Qp[0], qb = Qp[1];
    unsigned int qd[8] = {qa.x, qa.y, qa.z, qa.w, qb.x, qb.y, qb.z, qb.w};
    float x[4][8];
#pragma unroll
    for (int j = 0; j < 8; ++j) {
        x[0][j] = __builtin_amdgcn_cvt_f32_fp8(qd[j], 0);
        x[1][j] = __builtin_amdgcn_cvt_f32_fp8(qd[j], 1);
        x[2][j] = __builtin_amdgcn_cvt_f32_fp8(qd[j], 2);
        x[3][j] = __builtin_amdgcn_cvt_f32_fp8(qd[j], 3);
    }
    __syncthreads();

    const int gt   = tid >> 5;
    const int cmax = ((tid >> 6) << 1) + 1;   // wave-uniform loop bound
    for (int c = 0; c < cmax; ++c) {
        if (c < gt) {
            const unsigned short* Lb = LSTb + (size_t)c * CSZ * SIN + (tid * 8 - CSZ);
#pragma unroll
            for (int rr = 0; rr < 4; ++rr) {
                int ic = sidx[rr][c];
                if (ic >= 0) {
                    uint4 v = *(const uint4*)(Lb + (size_t)ic * SIN);
                    x[rr][0] += __uint_as_float(v.x << 16);
                    x[rr][1] += __uint_as_float(v.x & 0xFFFF0000u);
                    x[rr][2] += __uint_as_float(v.y << 16);
                    x[rr][3] += __uint_as_float(v.y & 0xFFFF0000u);
                    x[rr][4] += __uint_as_float(v.z << 16);
                    x[rr][5] += __uint_as_float(v.z & 0xFFFF0000u);
                    x[rr][6] += __uint_as_float(v.w << 16);
                    x[rr][7] += __uint_as_float(v.w & 0xFFFF0000u);
                }
            }
        }
    }

    float s[4] = {0.f, 0.f, 0.f, 0.f}, ss[4] = {0.f, 0.f, 0.f, 0.f};
#pragma unroll
    for (int rr = 0; rr < 4; ++rr)
#pragma unroll
        for (int e = 0; e < 8; ++e) {
            x[rr][e] = fmaxf(x[rr][e], 0.f);
            s[rr] += x[rr][e];
            ss[rr] += x[rr][e] * x[rr][e];
        }
#pragma unroll
    for (int o = 32; o; o >>= 1)
#pragma unroll
        for (int rr = 0; rr < 4; ++rr) {
            s[rr] += __shfl_xor(s[rr], o);
            ss[rr] += __shfl_xor(ss[rr], o);
        }
    const int wv = tid >> 6;
    if ((tid & 63) == 0)
#pragma unroll
        for (int rr = 0; rr < 4; ++rr) { wsum[wv][rr] = s[rr]; wsq[wv][rr] = ss[rr]; }
    __syncthreads();

    float g8[8], b8[8];
#pragma unroll
    for (int e = 0; e < 8; ++e) {
        g8[e] = gamma[tid * 8 + e];
        b8[e] = beta[tid * 8 + e];
    }
#pragma unroll
    for (int rr = 0; rr < 4; ++rr) {
        float ts  = wsum[0][rr] + wsum[1][rr] + wsum[2][rr] + wsum[3][rr];
        float tss = wsq[0][rr] + wsq[1][rr] + wsq[2][rr] + wsq[3][rr];
        const float mu8  = ts * (1.f / TOTD);
        const float var8 = tss * (1.f / TOTD) - mu8 * mu8;
        const float rstd = rsqrtf(var8 + 64.f * 1e-5f);
        float y[8];
#pragma unroll
        for (int e = 0; e < 8; ++e)
            y[e] = ((x[rr][e] - mu8) * rstd * g8[e] + b8[e]) * 8.f;   // H scale 8
        int p0 = __builtin_amdgcn_cvt_pk_fp8_f32(y[0], y[1], 0, false);
        p0     = __builtin_amdgcn_cvt_pk_fp8_f32(y[2], y[3], p0, true);
        int p1 = __builtin_amdgcn_cvt_pk_fp8_f32(y[4], y[5], 0, false);
        p1     = __builtin_amdgcn_cvt_pk_fp8_f32(y[6], y[7], p1, true);
        int2 o; o.x = p0; o.y = p1;
        ((int2*)(H8 + (size_t)(4 * qrow + rr) * TOTD))[tid] = o;
    }
}

// ------- GEMM2 (fp8): 128x128 tile, r4 pipeline + partial-softmax epilogue -------
__global__ __launch_bounds__(256)
void k_gemm2(const unsigned char* __restrict__ H,
             const unsigned char* __restrict__ W2,
             const float* __restrict__ b2,
             const int* __restrict__ idx,
             float* __restrict__ pm_,
             float* __restrict__ ps_,
             float* __restrict__ pt_) {
    const int K = TOTD;
    __shared__ __align__(16) unsigned char As[3 * 8192];
    __shared__ __align__(16) unsigned char Bs[3 * 8192];
    __shared__ int tidx[128];

    const int tid  = threadIdx.x;
    const int lane = tid & 63;
    const int wave = tid >> 6;
    const int wm = (wave >> 1) << 6;
    const int wn = (wave & 1) << 6;
    const int wg   = (blockIdx.x & 7) * 512 + (blockIdx.x >> 3);
    const int row0 = (wg >> 4) << 7;
    const int col0 = (wg & 15) << 7;
    const int g    = col0 >> 8;

    floatx16 acc00 = 0.f, acc01 = 0.f, acc10 = 0.f, acc11 = 0.f;

    const int lh    = lane >> 1;
    const int srow  = ((wave >> 1) << 5) + (lh ^ ((lh & 12) >> 2));
    const int skoff = ((wave & 1) << 5) + ((lane & 1) << 4);
    const unsigned char* Ag  = H  + (size_t)(row0 + srow) * K + skoff;
    const unsigned char* Ag2 = Ag + (size_t)64 * K;
    const unsigned char* Bg  = W2 + (size_t)(col0 + srow) * K + skoff;
    const unsigned char* Bg2 = Bg + (size_t)64 * K;
    unsigned char* Al = As + wave * 1024;
    unsigned char* Bl = Bs + wave * 1024;

    if (tid < 128) tidx[tid] = idx[(size_t)(row0 + tid) * NCB + g];

    gload16(Ag,        Al);
    gload16(Ag2,       Al + 4096);
    gload16(Bg,        Bl);
    gload16(Bg2,       Bl + 4096);
    gload16(Ag + 64,   Al + 8192);
    gload16(Ag2 + 64,  Al + 8192 + 4096);
    gload16(Bg + 64,   Bl + 8192);
    gload16(Bg2 + 64,  Bl + 8192 + 4096);

    const int ro = (lane << 5) ^ ((lane & 12) << 3);

    auto compute = [&](int cbuf) {
        const unsigned char* Ab = As + cbuf * 8192 + ((wm >> 5) << 11) + ro;
        const unsigned char* Bb = Bs + cbuf * 8192 + ((wn >> 5) << 11) + ro;
        intx8 a0 = *(const intx8*)Ab;
        intx8 b0 = *(const intx8*)Bb;
        intx8 a1 = *(const intx8*)(Ab + 2048);
        intx8 b1 = *(const intx8*)(Bb + 2048);
        MFMA64(acc00, a0, b0);
        MFMA64(acc10, a1, b0);
        MFMA64(acc01, a0, b1);
        MFMA64(acc11, a1, b1);
    };

    const int NI = K / 64;   // 32
    int cb = 0, nb = 2;
    for (int i = 0; i < NI - 1; ++i) {
        asm volatile("s_waitcnt vmcnt(4)" ::: "memory");
        SBAR();
        if (i + 2 < NI) {
            const int k0 = (i + 2) * 64;
            gload16(Ag + k0,  Al + nb * 8192);
            gload16(Ag2 + k0, Al + nb * 8192 + 4096);
            gload16(Bg + k0,  Bl + nb * 8192);
            gload16(Bg2 + k0, Bl + nb * 8192 + 4096);
        }
        compute(cb);
        cb = (cb + 1 == 3) ? 0 : cb + 1;
        nb = (nb + 1 == 3) ? 0 : nb + 1;
    }
    asm volatile("s_waitcnt vmcnt(0)" ::: "memory");
    SBAR();
    compute(cb);
    asm volatile("s_nop 7\n\ts_nop 7\n\ts_nop 7" ::: "memory");  // MFMA->VALU read spacing

    // ---- epilogue: per-row partials over this wave's 64-col window ----
    const int l31  = lane & 31;
    const int half = lane >> 5;
    const int slot = (col0 + wn) >> 6;   // 0..31
    const int coff = (col0 & 255) + wn;
    const float bc0 = b2[col0 + wn + l31];
    const float bc1 = b2[col0 + wn + 32 + l31];

    auto epi = [&](const floatx16& A0, const floatx16& A1, int mtoff) {
#pragma unroll
        for (int r = 0; r < 16; ++r) {
            const int lrow = wm + mtoff + (r & 3) + ((r >> 2) << 3) + (half << 2);
            const int ic   = tidx[lrow];
            const int tloc = ic - coff;
            float v0 = A0[r] * 0.0078125f + bc0;
            float v1 = A1[r] * 0.0078125f + bc1;
            float mm = fmaxf(v0, v1), tv = 0.f;
            if (ic >= 0) {
                if (l31 == tloc)      tv += v0;
                if (l31 + 32 == tloc) tv += v1;
            }
#pragma unroll
            for (int o = 1; o < 32; o <<= 1) mm = fmaxf(mm, __shfl_xor(mm, o));
            float sv = __expf(v0 - mm) + __expf(v1 - mm);
#pragma unroll
            for (int o = 1; o < 32; o <<= 1) { sv += __shfl_xor(sv, o); tv += __shfl_xor(tv, o); }
            if (l31 == 0) {
                const int row = row0 + lrow;
                pm_[(size_t)slot * NROWS + row] = mm;
                ps_[(size_t)slot * NROWS + row] = sv;
                pt_[(size_t)slot * NROWS + row] = tv;
            }
        }
    };
    epi(acc00, acc01, 0);
    epi(acc10, acc11, 32);
}

// ------- combine: merge 4 slots per (row, group), accumulate logprob + count -------
__global__ __launch_bounds__(256) void k_comb(const float* __restrict__ pm_,
                                              const float* __restrict__ ps_,
                                              const float* __restrict__ pt_,
                                              const int* __restrict__ idx,
                                              float* __restrict__ out) {
    const int i   = blockIdx.x * 256 + threadIdx.x;
    const int row = i & (NROWS - 1);
    const int g   = i >> 15;
    const int ic  = idx[(size_t)row * NCB + g];
    float lp = 0.f, cnt = 0.f;
    if (ic >= 0) {
        const size_t b = (size_t)(g * 4) * NROWS + row;
        float m0 = pm_[b], m1 = pm_[b + NROWS], m2 = pm_[b + 2 * NROWS], m3 = pm_[b + 3 * NROWS];
        float mm = fmaxf(fmaxf(m0, m1), fmaxf(m2, m3));
        float Z = ps_[b] * __expf(m0 - mm) + ps_[b + NROWS] * __expf(m1 - mm)
                + ps_[b + 2 * NROWS] * __expf(m2 - mm) + ps_[b + 3 * NROWS] * __expf(m3 - mm);
        float t = pt_[b] + pt_[b + NROWS] + pt_[b + 2 * NROWS] + pt_[b + 3 * NROWS];
        lp = t - (mm + __logf(Z));
        cnt = 1.f;
    }
#pragma unroll
    for (int o = 1; o < 64; o <<= 1) { lp += __shfl_xor(lp, o); cnt += __shfl_xor(cnt, o); }
    __shared__ float wred[8];
    const int lane = threadIdx.x & 63, wave = threadIdx.x >> 6;
    if (lane == 0) { wred[wave] = lp; wred[4 + wave] = cnt; }
    __syncthreads();
    if (threadIdx.x == 0) {
        atomicAdd(&out[0], wred[0] + wred[1] + wred[2] + wred[3]);
        atomicAdd(&out[1], wred[4] + wred[5] + wred[6] + wred[7]);
    }
}

extern "C" void kernel_launch(void* const* d_in, const int* in_sizes, int n_in,
                              void* d_out, int out_size, void* d_ws, size_t ws_size,
                              hipStream_t stream) {
    const float* predictor = (const float*)d_in[0];
    const int*   cbidx     = (const int*)d_in[1];
    const float* W1        = (const float*)d_in[2];
    const float* b1        = (const float*)d_in[3];
    const float* LS        = (const float*)d_in[4];
    const float* gamma     = (const float*)d_in[5];
    const float* beta      = (const float*)d_in[6];
    const float* W2        = (const float*)d_in[7];
    const float* b2        = (const float*)d_in[8];
    float* out = (float*)d_out;

    char* ws = (char*)d_ws;
    size_t off = 0;
    auto alloc = [&](size_t bytes) {
        char* p = ws + off;
        off += (bytes + 255) & ~(size_t)255;
        return p;
    };
    unsigned char* HrawQ = (unsigned char*)alloc((size_t)NROWS * TOTD);   // dead after k_ln -> pm/ps/pt alias
    unsigned char* R2    = (unsigned char*)alloc((size_t)NROWS * TOTD);   // pred8+W1_8, then H8
    unsigned char* W2_8  = (unsigned char*)alloc((size_t)TOTD * TOTD);
    unsigned short* LSTb = (unsigned short*)alloc((size_t)SIN * SIN * 2);

    unsigned char* pred8 = R2;
    unsigned char* W1_8  = R2 + (size_t)NROWS * PD;
    unsigned char* H8    = R2;
    float* pm_ = (float*)HrawQ;
    float* ps_ = pm_ + (size_t)32 * NROWS;
    float* pt_ = ps_ + (size_t)32 * NROWS;

    hipMemsetAsync(d_out, 0, 2 * sizeof(float), stream);

    k_cvtall<<<(NPRED + NW1C + NW2C) / 256, 256, 0, stream>>>(predictor, W1, W2,
                                                              pred8, W1_8, W2_8);
    k_tb<<<dim3(SIN / 32, SIN / 32), 256, 0, stream>>>(LS, LSTb);

    k_gemm1<<<16 * 256, 256, 0, stream>>>(pred8, W1_8, b1, HrawQ);
    k_ln<<<NROWS / 4, 256, 0, stream>>>(HrawQ, H8, LSTb, cbidx, gamma, beta);
    k_gemm2<<<16 * 256, 256, 0, stream>>>(H8, W2_8, b2, cbidx, pm_, ps_, pt_);
    k_comb<<<NROWS * NCB / 256, 256, 0, stream>>>(pm_, ps_, pt_, cbidx, out);
}